// Round 3
// baseline (366.081 us; speedup 1.0000x reference)
//
#include <hip/hip_runtime.h>

#define C_ 96
#define H_ 512
#define W_ 96
#define HW_ 49152        // H_*W_
#define CHW_ 4718592     // C_*HW_
#define PIT 104          // LDS row pitch in f16 elements (208 B, 16B-aligned rows)
#define REG 9984         // 96*PIT elements per region

typedef _Float16 f16x8 __attribute__((ext_vector_type(8)));
typedef _Float16 f16x4 __attribute__((ext_vector_type(4)));
typedef _Float16 f16x2 __attribute__((ext_vector_type(2)));
typedef float    f32x4 __attribute__((ext_vector_type(4)));
typedef int      i32x4 __attribute__((ext_vector_type(4)));

#define MFMA16 __builtin_amdgcn_mfma_f32_16x16x32_f16

// LDS-only barrier: order ds ops without draining vmcnt.
#define BAR() do { __builtin_amdgcn_sched_barrier(0); \
                   asm volatile("s_waitcnt lgkmcnt(0)" ::: "memory"); \
                   __builtin_amdgcn_s_barrier(); \
                   __builtin_amdgcn_sched_barrier(0); } while (0)

// Prep 1: fold BN into QKV weights + bias.
//   W'[o][c] = W[o][c]*inv[c],  b'[o] = qkv_b[o] + sum_c W[o][c]*shift[c]
__global__ void prep_kernel(const float* __restrict__ wq,
                            const float* __restrict__ gamma,
                            const float* __restrict__ beta,
                            const float* __restrict__ mean,
                            const float* __restrict__ var,
                            const float* __restrict__ qkvb,
                            _Float16* __restrict__ whf,
                            float* __restrict__ bprime)
{
    int i = blockIdx.x * 256 + threadIdx.x;
    if (i < 3 * C_ * C_) {
        int c = i % C_;
        float iv = gamma[c] * rsqrtf(var[c] + 1e-5f);
        whf[i] = (_Float16)(wq[i] * iv);
    }
    if (i < 3 * C_) {
        float acc = qkvb[i];
        for (int c = 0; c < C_; ++c) {
            float iv = gamma[c] * rsqrtf(var[c] + 1e-5f);
            acc += wq[i * C_ + c] * (beta[c] - mean[c] * iv);
        }
        bprime[i] = acc;
    }
}

// Prep 2: A = W_q'^T W_k'  (stored transposed: atm[c*96+c'] = A[c'][c])
//         g0[c] = sum_o b_q[o] * W_k'[o][c]
// S[q][k] = sum_c xn[k][c] * G[q][c] + (const over k, dropped), G = xn*A + g0.
__global__ void prep2_kernel(const float* __restrict__ wq,
                             const float* __restrict__ gamma,
                             const float* __restrict__ var,
                             const float* __restrict__ bprime,
                             _Float16* __restrict__ atm,
                             float* __restrict__ g0)
{
    int i = blockIdx.x * 256 + threadIdx.x;
    if (i >= 9216) return;
    int c = i / 96, cp = i % 96;
    float ivc  = gamma[c]  * rsqrtf(var[c]  + 1e-5f);
    float ivcp = gamma[cp] * rsqrtf(var[cp] + 1e-5f);
    float acc = 0.f;
    #pragma unroll 4
    for (int o = 0; o < 96; ++o)
        acc += wq[o * 96 + cp] * wq[(96 + o) * 96 + c];
    atm[c * 96 + cp] = (_Float16)(acc * ivc * ivcp);
    if (cp == 0) {
        float a2 = 0.f;
        #pragma unroll 4
        for (int o = 0; o < 96; ++o)
            a2 += bprime[o] * wq[(96 + o) * 96 + c];
        g0[c] = a2 * ivc;
    }
}

// D-layout -> B-frag exchange (validated in R2's Q path).
// in : v[nt] = M[row = own q][idx = 16nt+4q4+r] held as D[idx][q-col]
// out: fr[kk] = M[own q][idx = 32kk+8q4+e], e=0..7
__device__ __forceinline__ void xchg(const f32x4 v[6], float scale,
                                     int q4, int n16, f16x8 fr[3])
{
    int pq[6][2];
    #pragma unroll
    for (int nt = 0; nt < 6; ++nt) {
        #pragma unroll
        for (int jj = 0; jj < 2; ++jj) {
            f16x2 h;
            h[0] = (_Float16)(v[nt][2 * jj] * scale);
            h[1] = (_Float16)(v[nt][2 * jj + 1] * scale);
            pq[nt][jj] = __builtin_bit_cast(int, h);
        }
    }
    const int srcA = ((q4 & 1) << 5) | n16;
    const int srcB = srcA + 16;
    #pragma unroll
    for (int kk = 0; kk < 3; ++kk) {
        const int a0 = __shfl(pq[2 * kk][0], srcA), a1 = __shfl(pq[2 * kk][1], srcA);
        const int a2 = __shfl(pq[2 * kk][0], srcB), a3 = __shfl(pq[2 * kk][1], srcB);
        const int b0 = __shfl(pq[2 * kk + 1][0], srcA), b1 = __shfl(pq[2 * kk + 1][1], srcA);
        const int b2 = __shfl(pq[2 * kk + 1][0], srcB), b3 = __shfl(pq[2 * kk + 1][1], srcB);
        i32x4 u;
        u[0] = (q4 < 2) ? a0 : b0;
        u[1] = (q4 < 2) ? a1 : b1;
        u[2] = (q4 < 2) ? a2 : b2;
        u[3] = (q4 < 2) ? a3 : b3;
        fr[kk] = __builtin_bit_cast(f16x8, u);
    }
}

// One wg per (b,h). 6 waves, ONE barrier, 2 LDS regions (XN + XN^T).
// After the barrier every wave is fully independent:
//   G = xn*A + g0 ; S = xn*G^T ; softmax ; Z = P*xn ; O = Z*Wv'^T + bv ; +x
__global__ __launch_bounds__(384, 5) void attn_kernel(
    const float* __restrict__ x,
    const _Float16* __restrict__ whf,
    const _Float16* __restrict__ atm,
    const float* __restrict__ g0,
    const float* __restrict__ bprime,
    float* __restrict__ out)
{
    __shared__ __align__(16) _Float16 smem[2 * REG];
    _Float16* XN  = smem;           // xn[w][c]
    _Float16* XNT = smem + REG;     // xn^T[c][w]

    const int tid  = threadIdx.x;
    const int ws   = tid >> 6;
    const int lane = tid & 63;
    const int q4   = lane >> 4;
    const int n16  = lane & 15;
    const int w0   = 16 * ws + 4 * q4;
    const int qrow = 16 * ws + n16;   // this lane's q (= w position)

    const int bh = blockIdx.x;
    const size_t base = (size_t)(bh >> 9) * CHW_ + (size_t)(bh & 511) * W_;

    // ---- stage: x -> XN[w][c] (scalar) and XNT[c][w] (b64) ----
    {
        f32x4 xr[6];
        #pragma unroll
        for (int t = 0; t < 6; ++t)
            xr[t] = *(const f32x4*)(x + base + (size_t)(16 * t + n16) * HW_ + w0);
        #pragma unroll
        for (int t = 0; t < 6; ++t) {
            const int c = 16 * t + n16;
            f16x4 pk;
            #pragma unroll
            for (int r = 0; r < 4; ++r) pk[r] = (_Float16)xr[t][r];
            *(f16x4*)(XNT + c * PIT + w0) = pk;
            #pragma unroll
            for (int r = 0; r < 4; ++r)
                XN[(w0 + r) * PIT + c] = (_Float16)xr[t][r];
        }
    }
    BAR();   // the only barrier

    // ---- G-pass: G^T[c][q] = A^T[c][:] . xn[q][:] + g0[c] ----
    f32x4 gac[6];
    #pragma unroll
    for (int nt = 0; nt < 6; ++nt)
        gac[nt] = *(const f32x4*)(g0 + 16 * nt + 4 * q4);
    #pragma unroll
    for (int kk = 0; kk < 3; ++kk) {
        const f16x8 bfr = *(const f16x8*)(XN + qrow * PIT + 32 * kk + 8 * q4);
        #pragma unroll
        for (int nt = 0; nt < 6; ++nt) {
            const f16x8 afr = *(const f16x8*)(atm + (16 * nt + n16) * 96 + 32 * kk + 8 * q4);
            gac[nt] = MFMA16(afr, bfr, gac[nt], 0, 0, 0);
        }
    }
    f16x8 gf[3];
    xchg(gac, 1.0f, q4, n16, gf);

    // ---- S-pass: S^T[k][q] = xn[k][:] . G[q][:] ----
    f32x4 sacc[6];
    #pragma unroll
    for (int nt = 0; nt < 6; ++nt) sacc[nt] = f32x4{0.f, 0.f, 0.f, 0.f};
    #pragma unroll
    for (int kk = 0; kk < 3; ++kk) {
        #pragma unroll
        for (int nt = 0; nt < 6; ++nt) {
            const f16x8 afr = *(const f16x8*)(XN + (16 * nt + n16) * PIT + 32 * kk + 8 * q4);
            sacc[nt] = MFMA16(afr, gf[kk], sacc[nt], 0, 0, 0);
        }
    }

    // ---- softmax over k (lane owns its q-row; reduce across q4 pair) ----
    float mr0 = sacc[0][0], mr1 = sacc[0][1], mr2 = sacc[0][2], mr3 = sacc[0][3];
    #pragma unroll
    for (int nt = 1; nt < 6; ++nt) {
        mr0 = fmaxf(mr0, sacc[nt][0]); mr1 = fmaxf(mr1, sacc[nt][1]);
        mr2 = fmaxf(mr2, sacc[nt][2]); mr3 = fmaxf(mr3, sacc[nt][3]);
    }
    float m = fmaxf(fmaxf(mr0, mr1), fmaxf(mr2, mr3));
    m = fmaxf(m, __shfl_xor(m, 16));
    m = fmaxf(m, __shfl_xor(m, 32));
    float sr0 = 0.f, sr1 = 0.f, sr2 = 0.f, sr3 = 0.f;
    #pragma unroll
    for (int nt = 0; nt < 6; ++nt) {
        sacc[nt][0] = __expf(sacc[nt][0] - m); sr0 += sacc[nt][0];
        sacc[nt][1] = __expf(sacc[nt][1] - m); sr1 += sacc[nt][1];
        sacc[nt][2] = __expf(sacc[nt][2] - m); sr2 += sacc[nt][2];
        sacc[nt][3] = __expf(sacc[nt][3] - m); sr3 += sacc[nt][3];
    }
    float s = (sr0 + sr1) + (sr2 + sr3);
    s += __shfl_xor(s, 16);
    s += __shfl_xor(s, 32);
    const float pinv = 1.0f / s;

    f16x8 pa[3];
    xchg(sacc, pinv, q4, n16, pa);   // pa[kk] = P[own q][k = 32kk+8q4+e]

    // ---- residual reload (issued here; lands under Z/O passes) ----
    float xv[6][4];
    #pragma unroll
    for (int ot = 0; ot < 6; ++ot)
        #pragma unroll
        for (int r = 0; r < 4; ++r)
            xv[ot][r] = x[base + (size_t)(16 * ot + 4 * q4 + r) * HW_ + qrow];

    // ---- Z-pass: Z^T[c][q] = xn^T[c][:] . P[q][:] ----
    f32x4 zac[6];
    #pragma unroll
    for (int nt = 0; nt < 6; ++nt) zac[nt] = f32x4{0.f, 0.f, 0.f, 0.f};
    #pragma unroll
    for (int kk = 0; kk < 3; ++kk) {
        #pragma unroll
        for (int nt = 0; nt < 6; ++nt) {
            const f16x8 afr = *(const f16x8*)(XNT + (16 * nt + n16) * PIT + 32 * kk + 8 * q4);
            zac[nt] = MFMA16(afr, pa[kk], zac[nt], 0, 0, 0);
        }
    }
    f16x8 zf[3];
    xchg(zac, 1.0f, q4, n16, zf);

    // ---- O-pass: O^T[cv][q] = Wv'[cv][:] . Z[q][:] + bv[cv] ----
    f32x4 oacc[6];
    #pragma unroll
    for (int ot = 0; ot < 6; ++ot)
        oacc[ot] = *(const f32x4*)(bprime + 192 + 16 * ot + 4 * q4);
    #pragma unroll
    for (int kk = 0; kk < 3; ++kk) {
        #pragma unroll
        for (int ot = 0; ot < 6; ++ot) {
            const f16x8 afr = *(const f16x8*)(whf + (192 + 16 * ot + n16) * 96 + 32 * kk + 8 * q4);
            oacc[ot] = MFMA16(afr, zf[kk], oacc[ot], 0, 0, 0);
        }
    }

    // ---- epilogue: + residual, store (16-lane 64B-contiguous groups) ----
    #pragma unroll
    for (int ot = 0; ot < 6; ++ot)
        #pragma unroll
        for (int r = 0; r < 4; ++r)
            out[base + (size_t)(16 * ot + 4 * q4 + r) * HW_ + qrow] =
                oacc[ot][r] + xv[ot][r];
}

extern "C" void kernel_launch(void* const* d_in, const int* in_sizes, int n_in,
                              void* d_out, int out_size, void* d_ws, size_t ws_size,
                              hipStream_t stream)
{
    const float* x     = (const float*)d_in[0];
    const float* gamma = (const float*)d_in[1];
    const float* beta  = (const float*)d_in[2];
    const float* mean  = (const float*)d_in[3];
    const float* var   = (const float*)d_in[4];
    const float* qkvw  = (const float*)d_in[5];
    const float* qkvb  = (const float*)d_in[6];
    float* out = (float*)d_out;

    _Float16* whf    = (_Float16*)d_ws;                     // [0, 55296)
    float*    bprime = (float*)((char*)d_ws + 55296);       // [55296, 56448)
    _Float16* atm    = (_Float16*)((char*)d_ws + 56448);    // [56448, 74880)
    float*    g0v    = (float*)((char*)d_ws + 74880);       // [74880, 75264)

    prep_kernel<<<108, 256, 0, stream>>>(qkvw, gamma, beta, mean, var, qkvb, whf, bprime);
    prep2_kernel<<<36, 256, 0, stream>>>(qkvw, gamma, var, bprime, atm, g0v);
    attn_kernel<<<4096, 384, 0, stream>>>(x, whf, atm, g0v, bprime, out);
}